// Round 19
// baseline (75.023 us; speedup 1.0000x reference)
//
#include <hip/hip_runtime.h>
#include <math.h>

typedef unsigned short u16;
typedef __attribute__((ext_vector_type(8))) short bf16x8;
typedef __attribute__((ext_vector_type(4))) float f32x4;

#define BB 2
#define NN 512
#define SCALEF 0.17677669529663687f  // 1/sqrt(16 + 4*4)

__device__ __forceinline__ u16 f2bf(float x) {
  union { float f; unsigned u; } c; c.f = x;
  unsigned r = (c.u + 0x7FFFu + ((c.u >> 16) & 1u)) >> 16;
  return (u16)r;
}
__device__ __forceinline__ float bf2f(u16 h) {
  union { unsigned u; float f; } c; c.u = ((unsigned)h) << 16;
  return c.f;
}
__device__ __forceinline__ void pack8(const float* v, bf16x8& h, bf16x8& l) {
#pragma unroll
  for (int j = 0; j < 8; ++j) {
    u16 hi = f2bf(v[j]);
    h[j] = (short)hi;
    l[j] = (short)f2bf(v[j] - bf2f(hi));
  }
}
#define MFMA3(ACC, AH, AL, BH, BL)                                              \
  ACC = __builtin_amdgcn_mfma_f32_16x16x32_bf16(AH, BH, ACC, 0, 0, 0);          \
  ACC = __builtin_amdgcn_mfma_f32_16x16x32_bf16(AH, BL, ACC, 0, 0, 0);          \
  ACC = __builtin_amdgcn_mfma_f32_16x16x32_bf16(AL, BH, ACC, 0, 0, 0);

// ====== bf16 direct-global MFMA tile (used by k_attn QK) ======
template<int MR, int NF>
__device__ __forceinline__ void mfma_tile(
    const u16* __restrict__ Ah, const u16* __restrict__ Al, int lda,
    const u16* __restrict__ Bh, const u16* __restrict__ Bl, int ldb,
    int kBeg, int kEnd, int arow, int bcol, f32x4 (&acc)[MR][NF]) {
  const int lane = threadIdx.x & 63;
  const int rr = lane & 15, kg = lane >> 4;
  const u16* pah = Ah + (size_t)(arow + rr) * lda + kg * 8;
  const u16* pal = Al + (size_t)(arow + rr) * lda + kg * 8;
  const u16* pbh = Bh + (size_t)(bcol + rr) * ldb + kg * 8;
  const u16* pbl = Bl + (size_t)(bcol + rr) * ldb + kg * 8;
#pragma unroll 2
  for (int k0 = kBeg; k0 < kEnd; k0 += 32) {
    bf16x8 a_h[MR], a_l[MR], b_h[NF], b_l[NF];
#pragma unroll
    for (int m = 0; m < MR; ++m) {
      a_h[m] = *(const bf16x8*)(pah + (size_t)m * 16 * lda + k0);
      a_l[m] = *(const bf16x8*)(pal + (size_t)m * 16 * lda + k0);
    }
#pragma unroll
    for (int f = 0; f < NF; ++f) {
      b_h[f] = *(const bf16x8*)(pbh + (size_t)f * 16 * ldb + k0);
      b_l[f] = *(const bf16x8*)(pbl + (size_t)f * 16 * ldb + k0);
    }
#pragma unroll
    for (int m = 0; m < MR; ++m)
#pragma unroll
      for (int f = 0; f < NF; ++f) { MFMA3(acc[m][f], a_h[m], a_l[m], b_h[f], b_l[f]) }
  }
}

// ---------------- k_input: projections + weight composition ----------------
__global__ __launch_bounds__(512) void k_input(
    const float* __restrict__ hidden,
    const float* __restrict__ W_qk, const float* __restrict__ b_qk,
    const float* __restrict__ W_vs, const float* __restrict__ b_vs,
    const float* __restrict__ W_pv, const float* __restrict__ b_pv,
    const float* __restrict__ W_pqk, const float* __restrict__ b_pqk,
    const float* __restrict__ W_so, const float* __restrict__ b_so,
    const float* __restrict__ W_po, const float* __restrict__ b_po,
    const float* __restrict__ W_fp, const float* __restrict__ b_fp,
    u16* __restrict__ QKh, u16* __restrict__ QKl,
    u16* __restrict__ VRh, u16* __restrict__ VRl,
    float* __restrict__ QPf,
    u16* __restrict__ WCTh, u16* __restrict__ WCTl,
    float* __restrict__ bc, float* __restrict__ Wdf) {
  const int tid = threadIdx.x;
  if (blockIdx.x >= 21) {
    const int cx = blockIdx.x - 21, ky = blockIdx.y;
    if (ky < 10) {
      // WCT tile: c in [cx*48,+48), k in [ky*48,+48); contraction m = 384
      const int w = tid >> 6, lane = tid & 63;
      if (w >= 3) return;
      const int rr = lane & 15, kg = lane >> 4;
      const int c0 = cx * 48;
      const int kbase = ky * 48 + w * 16;
      const float* Wop; int moff;
      if (kbase < 192) { Wop = W_so + (size_t)kbase * 384; moff = 0; }
      else             { Wop = W_po + (size_t)(kbase - 192) * 384; moff = 384; }
      f32x4 acc[3] = {};
      const float* pa = Wop + (size_t)rr * 384 + kg * 8;
      const float* pw = W_fp + (size_t)moff * 384 + c0 + rr;
      for (int m0 = 0; m0 < 384; m0 += 32) {
        bf16x8 a_h, a_l, b_h[3], b_l[3];
        float v[8];
        *(float4*)&v[0] = *(const float4*)(pa + m0);
        *(float4*)&v[4] = *(const float4*)(pa + m0 + 4);
        pack8(v, a_h, a_l);
        const float* bp0 = pw + (size_t)(m0 + kg * 8) * 384;
#pragma unroll
        for (int f = 0; f < 3; ++f) {
          float u[8];
#pragma unroll
          for (int j = 0; j < 8; ++j) u[j] = bp0[(size_t)j * 384 + f * 16];
          pack8(u, b_h[f], b_l[f]);
        }
#pragma unroll
        for (int f = 0; f < 3; ++f) { MFMA3(acc[f], a_h, a_l, b_h[f], b_l[f]) }
      }
      const int rb = (lane >> 4) << 2, cc = lane & 15;
#pragma unroll
      for (int f = 0; f < 3; ++f) {
        int c = c0 + f * 16 + cc;
#pragma unroll
        for (int r = 0; r < 4; ++r) {
          int k = kbase + rb + r;
          float vv = acc[f][r];
          u16 hi = f2bf(vv);
          WCTh[(size_t)c * 480 + k] = hi;
          WCTl[(size_t)c * 480 + k] = f2bf(vv - bf2f(hi));
        }
      }
      return;
    }
    if (ky == 10) {
      // bc: 8 blocks x 48 cols; 8-way K-split
      const int colL = tid >> 3, part = tid & 7;
      if (colL >= 48) return;
      const int col = cx * 48 + colL;
      const float* bv = (part < 4) ? b_so : b_po;
      const int m0 = (part & 3) * 96;
      const float* wrow = W_fp + (size_t)part * 96 * 384 + col;
      float s0 = 0.f, s1 = 0.f, s2 = 0.f, s3 = 0.f;
#pragma unroll
      for (int i = 0; i < 96; i += 4) {
        s0 += bv[m0 + i]     * wrow[(size_t)(i)     * 384];
        s1 += bv[m0 + i + 1] * wrow[(size_t)(i + 1) * 384];
        s2 += bv[m0 + i + 2] * wrow[(size_t)(i + 2) * 384];
        s3 += bv[m0 + i + 3] * wrow[(size_t)(i + 3) * 384];
      }
      float s = (s0 + s1) + (s2 + s3);
      s += __shfl_down(s, 4, 8);
      s += __shfl_down(s, 2, 8);
      s += __shfl_down(s, 1, 8);
      if (part == 0) bc[col] = s + b_fp[col];
      return;
    }
    if (ky == 11) {
      // Wd: 8 blocks x 36 j-rows x 3 comps; 4-way K-split (+bd)
      const int out = tid >> 2, part = tid & 3;
      if (out < 108) {
        const int j = cx * 36 + out / 3, c = out - (out / 3) * 3;
        const float* src = W_po + (size_t)j * 384 + c + (size_t)part * 96;
        float s0 = 0.f, s1 = 0.f;
#pragma unroll
        for (int kk = 0; kk < 32; kk += 2) {
          s0 += src[3 * kk];
          s1 += src[3 * kk + 3];
        }
        float s = s0 + s1;
        s += __shfl_down(s, 2, 4);
        s += __shfl_down(s, 1, 4);
        if (part == 0) Wdf[j * 3 + c] = s * (1.0f / 128.f);
      } else if (cx == 0 && tid >= 432 && tid < 480) {
        int g = tid - 432, c = g >> 4, k0 = g & 15;
        float s = 0.f;
#pragma unroll
        for (int kk = 0; kk < 8; ++kk) s += b_po[3 * (k0 * 8 + kk) + c];
        for (int d = 8; d; d >>= 1) s += __shfl_down(s, d, 16);
        if (k0 == 0) Wdf[864 + c] = s * (1.0f / 128.f);
      }
      return;
    }
    return;
  }

  // ---- projection blocks ----
  __shared__ f32x4 CB[7][2][3][64];
  const int w = tid >> 6, lane = tid & 63;
  const int rr = lane & 15, kg = lane >> 4;
  const int row0 = blockIdx.y * 32, col0 = blockIdx.x * 48;

  const float* W; const float* bias; int Ns, region;
  if (col0 < 384)      { W = W_qk;  Ns = 384; bias = b_qk + col0;          W += col0;       region = 0; }
  else if (col0 < 576) { W = W_vs;  Ns = 192; bias = b_vs + (col0 - 384);  W += col0 - 384; region = 1; }
  else if (col0 < 864) { W = W_pv;  Ns = 288; bias = b_pv + (col0 - 576);  W += col0 - 576; region = 1; }
  else                 { W = W_pqk; Ns = 144; bias = b_pqk + (col0 - 864); W += col0 - 864; region = 2; }

  f32x4 acc[2][3] = {};
  const float* pa = hidden + (size_t)(row0 + rr) * 384 + kg * 8;
  const float* pw = W + rr;
  for (int k0 = w * 32; k0 < 384; k0 += 256) {
    bf16x8 a_h[2], a_l[2], b_h[3], b_l[3];
#pragma unroll
    for (int m = 0; m < 2; ++m) {
      float v[8];
      *(float4*)&v[0] = *(const float4*)(pa + (size_t)m * 16 * 384 + k0);
      *(float4*)&v[4] = *(const float4*)(pa + (size_t)m * 16 * 384 + k0 + 4);
      pack8(v, a_h[m], a_l[m]);
    }
    const float* bp0 = pw + (size_t)(k0 + kg * 8) * Ns;
#pragma unroll
    for (int f = 0; f < 3; ++f) {
      float v[8];
#pragma unroll
      for (int j = 0; j < 8; ++j) v[j] = bp0[(size_t)j * Ns + f * 16];
      pack8(v, b_h[f], b_l[f]);
    }
#pragma unroll
    for (int m = 0; m < 2; ++m)
#pragma unroll
      for (int f = 0; f < 3; ++f) { MFMA3(acc[m][f], a_h[m], a_l[m], b_h[f], b_l[f]) }
  }
  if (w) {
#pragma unroll
    for (int m = 0; m < 2; ++m)
#pragma unroll
      for (int f = 0; f < 3; ++f) CB[w - 1][m][f][lane] = acc[m][f];
  }
  __syncthreads();
  if (w) return;
#pragma unroll
  for (int wv = 0; wv < 7; ++wv)
#pragma unroll
    for (int m = 0; m < 2; ++m)
#pragma unroll
      for (int f = 0; f < 3; ++f) acc[m][f] += CB[wv][m][f][lane];

  const int rb = (lane >> 4) << 2, cc = lane & 15;
  if (region == 0) {
#pragma unroll
    for (int f = 0; f < 3; ++f) {
      int n = col0 + f * 16 + cc;
      float bv = bias[f * 16 + cc];
#pragma unroll
      for (int m = 0; m < 2; ++m)
#pragma unroll
        for (int r = 0; r < 4; ++r) {
          float v = acc[m][f][r] + bv;
          int row = row0 + m * 16 + rb + r;
          u16 hi = f2bf(v);
          QKh[(size_t)row * 384 + n] = hi;
          QKl[(size_t)row * 384 + n] = f2bf(v - bf2f(hi));
        }
    }
  } else if (region == 2) {
#pragma unroll
    for (int f = 0; f < 3; ++f) {
      int c = (col0 - 864) + f * 16 + cc;
      float bv = bias[f * 16 + cc];
#pragma unroll
      for (int m = 0; m < 2; ++m)
#pragma unroll
        for (int r = 0; r < 4; ++r)
          QPf[(size_t)(row0 + m * 16 + rb + r) * 144 + c] = acc[m][f][r] + bv;
    }
  } else {
    // V region: row-major hi/lo
#pragma unroll
    for (int f = 0; f < 3; ++f) {
      int c = (col0 - 384) + f * 16 + cc;
      float bv = bias[f * 16 + cc];
#pragma unroll
      for (int m = 0; m < 2; ++m)
#pragma unroll
        for (int r = 0; r < 4; ++r) {
          float v = acc[m][f][r] + bv;
          int row = row0 + m * 16 + rb + r;
          u16 hi = f2bf(v);
          VRh[(size_t)row * 480 + c] = hi;
          VRl[(size_t)row * 480 + c] = f2bf(v - bf2f(hi));
        }
    }
  }
}

// ---- k_attn: attn logits (136) + VC tiles (64) + VCd (3), per batch; all co-resident ----
__global__ __launch_bounds__(512) void k_attn(
    const u16* __restrict__ QKh, const u16* __restrict__ QKl,
    const float* __restrict__ QPf,
    const u16* __restrict__ VRh, const u16* __restrict__ VRl,
    const u16* __restrict__ WCTh, const u16* __restrict__ WCTl,
    const float* __restrict__ Wdf,
    float* __restrict__ ATTf, u16* __restrict__ VCTh, u16* __restrict__ VCTl,
    float* __restrict__ VCdT) {
  __shared__ __align__(16) char smem[70912];
  const int tid = threadIdx.x;
  const int b = blockIdx.z;
  if (blockIdx.x >= 136) {
    const int xx = blockIdx.x - 136;
    if (xx < 64) {
      // VC tile: 32 tokens x 96 cols, K=480; 8 waves = {2 col-halves} x {4-way K-split}
      f32x4 (*CB)[2][3][64] = (f32x4 (*)[2][3][64])smem;  // [6][2][3][64] = 36864 B
      u16 (*Dh)[32] = (u16 (*)[32])(smem + 36864);        // [96][32] 6144 B
      u16 (*Dl)[32] = (u16 (*)[32])(smem + 43008);        // 6144 B
      const int tile = xx & 15, cg = xx >> 4;
      const int row0 = tile * 32, c0 = cg * 96;
      const int w = tid >> 6, lane = tid & 63;
      const int h2 = w & 1, p = w >> 1;
      const int rr = lane & 15, kg = lane >> 4;
      const u16* pah = VRh + (size_t)(b * NN + row0 + rr) * 480 + kg * 8;
      const u16* pal = VRl + (size_t)(b * NN + row0 + rr) * 480 + kg * 8;
      const u16* pbh = WCTh + (size_t)(c0 + h2 * 48 + rr) * 480 + kg * 8;
      const u16* pbl = WCTl + (size_t)(c0 + h2 * 48 + rr) * 480 + kg * 8;
      f32x4 acc[2][3] = {};
      for (int k0 = p * 32; k0 < 480; k0 += 128) {
        bf16x8 a_h[2], a_l[2], b_h[3], b_l[3];
#pragma unroll
        for (int m = 0; m < 2; ++m) {
          a_h[m] = *(const bf16x8*)(pah + (size_t)m * 16 * 480 + k0);
          a_l[m] = *(const bf16x8*)(pal + (size_t)m * 16 * 480 + k0);
        }
#pragma unroll
        for (int f = 0; f < 3; ++f) {
          b_h[f] = *(const bf16x8*)(pbh + (size_t)f * 16 * 480 + k0);
          b_l[f] = *(const bf16x8*)(pbl + (size_t)f * 16 * 480 + k0);
        }
#pragma unroll
        for (int m = 0; m < 2; ++m)
#pragma unroll
          for (int f = 0; f < 3; ++f) { MFMA3(acc[m][f], a_h[m], a_l[m], b_h[f], b_l[f]) }
      }
      if (p) {
#pragma unroll
        for (int m = 0; m < 2; ++m)
#pragma unroll
          for (int f = 0; f < 3; ++f) CB[h2 * 3 + p - 1][m][f][lane] = acc[m][f];
      }
      __syncthreads();
      if (p == 0) {
#pragma unroll
        for (int part = 0; part < 3; ++part)
#pragma unroll
          for (int m = 0; m < 2; ++m)
#pragma unroll
            for (int f = 0; f < 3; ++f) acc[m][f] += CB[h2 * 3 + part][m][f][lane];
        const int rb = (lane >> 4) << 2, cc = lane & 15;
#pragma unroll
        for (int m = 0; m < 2; ++m)
#pragma unroll
          for (int f = 0; f < 3; ++f)
#pragma unroll
            for (int r = 0; r < 4; ++r) {
              float v = acc[m][f][r];
              u16 hi = f2bf(v);
              Dh[h2 * 48 + f * 16 + cc][m * 16 + rb + r] = hi;
              Dl[h2 * 48 + f * 16 + cc][m * 16 + rb + r] = f2bf(v - bf2f(hi));
            }
      }
      __syncthreads();
      for (int u = tid; u < 768; u += 512) {
        int buf = u >= 384;
        int v2 = u - buf * 384;
        int col = v2 >> 2, seg = v2 & 3;
        const u16* src = (buf ? Dl[col] : Dh[col]) + seg * 8;
        u16* dst = (buf ? VCTl : VCTh) + ((size_t)b * 384 + c0 + col) * 512 + row0 + seg * 8;
        *(uint4*)dst = *(const uint4*)src;
      }
      return;
    }
    // VCd column c: VCd[b][c][token] = sum_j V_p[token][j] * Wd[j][c]
    const int c = xx - 64;
    float* WdL = (float*)smem;
    for (int i = tid; i < 288; i += 512) WdL[i] = Wdf[i * 3 + c];
    __syncthreads();
    const u16* vh = VRh + (size_t)(b * NN + tid) * 480 + 192;
    const u16* vl = VRl + (size_t)(b * NN + tid) * 480 + 192;
    float s0 = 0.f, s1 = 0.f;
#pragma unroll 4
    for (int j = 0; j < 288; j += 2) {
      s0 += (bf2f(vh[j]) + bf2f(vl[j])) * WdL[j];
      s1 += (bf2f(vh[j + 1]) + bf2f(vl[j + 1])) * WdL[j + 1];
    }
    VCdT[((size_t)b * 3 + c) * 512 + tid] = s0 + s1;
    return;
  }
  // ---- attention logits path ----
  float (*Pi)[244] = (float (*)[244])smem;             // 31232 B
  float (*Pj)[244] = (float (*)[244])(smem + 31232);   // 31232 B
  float* Sf = (float*)(smem + 62464);                  // 8448 B
  int t = blockIdx.x, ti_ = 0;
  while (t >= 16 - ti_) { t -= 16 - ti_; ++ti_; }
  const int tj_ = ti_ + t;
  const int i0 = ti_ * 32, j0 = tj_ * 32;
  const bool offdiag = (tj_ != ti_);
  for (int u = tid; u < 3072; u += 512) {
    int side = (u >= 1536) ? 1 : 0;
    int rem = u - side * 1536;
    int row = rem / 48, hp = rem - row * 48;
    int grow = b * NN + (side ? j0 : i0) + row;
    const float* p = QPf + (size_t)grow * 144 + hp * 3;
    float x = p[0], y = p[1], z = p[2];
    float n2 = x * x + y * y + z * z;
    float inv = __frsqrt_rn(n2 + 1e-12f);
    float* dst = side ? &Pj[row][0] : &Pi[row][0];
    ((float4*)dst)[hp] = make_float4(x, y, z, n2);
    dst[192 + hp] = inv;
  }
  __syncthreads();
  const int h = tid >> 8;
  const int t8 = tid & 255;
  const int tj = t8 & 15, ti = t8 >> 4;
  {
    float a00 = 0.f, a01 = 0.f, a10 = 0.f, a11 = 0.f;
    const float4* A0 = (const float4*)&Pi[ti][0];
    const float4* A1 = (const float4*)&Pi[ti + 16][0];
    const float4* B0 = (const float4*)&Pj[tj][0];
    const float4* B1 = (const float4*)&Pj[tj + 16][0];
    const float* iA0 = &Pi[ti][192];
    const float* iA1 = &Pi[ti + 16][192];
    const float* iB0 = &Pj[tj][192];
    const float* iB1 = &Pj[tj + 16][192];
    const int hpB = h * 24, hpE = hpB + 24;
#pragma unroll 4
    for (int hp = hpB; hp < hpE; ++hp) {
      float4 p0 = A0[hp], p1 = A1[hp], q0 = B0[hp], q1 = B1[hp];
      float va0 = iA0[hp], va1 = iA1[hp], vb0 = iB0[hp], vb1 = iB1[hp];
      {
        float dot = p0.x * q0.x + p0.y * q0.y + p0.z * q0.z;
        float d2 = fmaxf(fmaf(-2.f, dot, p0.w + q0.w), 0.f) + 1e-12f;
        a00 += d2 * __frsqrt_rn(d2) + dot * (va0 * vb0);
      }
      {
        float dot = p0.x * q1.x + p0.y * q1.y + p0.z * q1.z;
        float d2 = fmaxf(fmaf(-2.f, dot, p0.w + q1.w), 0.f) + 1e-12f;
        a01 += d2 * __frsqrt_rn(d2) + dot * (va0 * vb1);
      }
      {
        float dot = p1.x * q0.x + p1.y * q0.y + p1.z * q0.z;
        float d2 = fmaxf(fmaf(-2.f, dot, p1.w + q0.w), 0.f) + 1e-12f;
        a10 += d2 * __frsqrt_rn(d2) + dot * (va1 * vb0);
      }
      {
        float dot = p1.x * q1.x + p1.y * q1.y + p1.z * q1.z;
        float d2 = fmaxf(fmaf(-2.f, dot, p1.w + q1.w), 0.f) + 1e-12f;
        a11 += d2 * __frsqrt_rn(d2) + dot * (va1 * vb1);
      }
    }
    Sf[h * 1056 + ti * 33 + tj] = a00;
    Sf[h * 1056 + ti * 33 + tj + 16] = a01;
    Sf[h * 1056 + (ti + 16) * 33 + tj] = a10;
    Sf[h * 1056 + (ti + 16) * 33 + tj + 16] = a11;
  }
  const int w = tid >> 6, lane = tid & 63;
  const int dir = w >> 2, sub = w & 3;
  f32x4 q[1][1] = {};
  if (dir == 0) {
    int arow = b * NN + i0 + (sub >> 1) * 16;
    int brow = b * NN + j0 + (sub & 1) * 16;
    mfma_tile<1, 1>(QKh, QKl, 384, QKh + 192, QKl + 192, 384, 0, 192, arow, brow, q);
  } else if (offdiag) {
    int arow = b * NN + j0 + (sub >> 1) * 16;
    int brow = b * NN + i0 + (sub & 1) * 16;
    mfma_tile<1, 1>(QKh, QKl, 384, QKh + 192, QKl + 192, 384, 0, 192, arow, brow, q);
  }
  __syncthreads();
  const int rl = (sub >> 1) * 16 + ((lane >> 4) << 2);
  const int cl = (sub & 1) * 16 + (lane & 15);
  float* Cb = ATTf + (size_t)b * NN * NN;
  if (dir == 0) {
#pragma unroll
    for (int r = 0; r < 4; ++r)
      Cb[(size_t)(i0 + rl + r) * NN + j0 + cl] =
          q[0][0][r] + Sf[(rl + r) * 33 + cl] + Sf[1056 + (rl + r) * 33 + cl];
  } else if (offdiag) {
#pragma unroll
    for (int r = 0; r < 4; ++r)
      Cb[(size_t)(j0 + rl + r) * NN + i0 + cl] =
          q[0][0][r] + Sf[cl * 33 + rl + r] + Sf[1056 + cl * 33 + rl + r];
  }
}

// ---------------- k_pv_out: out_res = (Praw@VC)/rs + bc ; out_xyz = xyz + (Praw@VCd)/rs + bd ----------------
__global__ __launch_bounds__(512) void k_pv_out(
    const float* __restrict__ ATTf,
    const u16* __restrict__ VCTh, const u16* __restrict__ VCTl,
    const float* __restrict__ VCdT, const float* __restrict__ bc,
    const float* __restrict__ Wdf, const float* __restrict__ xyz,
    float* __restrict__ out_res, float* __restrict__ out_xyz) {
  const int tid = threadIdx.x;
  const int b = blockIdx.z;
  const int row0 = blockIdx.y * 16;
  if (blockIdx.x == 8) {
    const int part = tid & 7, rest = tid >> 3;
    const int c = rest % 3, lt = rest / 3;
    if (lt < 16) {
      const float* arow = ATTf + ((size_t)b * NN + row0 + lt) * NN + part * 64;
      const float* vcd = VCdT + ((size_t)b * 3 + c) * 512 + part * 64;
      float s = 0.f, rs = 0.f;
#pragma unroll 8
      for (int kk = 0; kk < 64; ++kk) {
        float e = __expf(arow[kk] * SCALEF);
        s += e * vcd[kk];
        rs += e;
      }
#pragma unroll
      for (int d = 4; d; d >>= 1) { s += __shfl_down(s, d, 8); rs += __shfl_down(rs, d, 8); }
      if (part == 0) {
        size_t idx = ((size_t)b * NN + row0 + lt) * 3 + c;
        out_xyz[idx] = xyz[idx] + s / rs + Wdf[864 + c];
      }
    }
    return;
  }
  __shared__ f32x4 CB[7][3][64];
  __shared__ float RS[7][64];
  const int w = tid >> 6, lane = tid & 63;
  const int rr = lane & 15, kg = lane >> 4;
  const int col0 = blockIdx.x * 48;
  const float* pa = ATTf + (size_t)(b * NN + row0 + rr) * NN + kg * 8;
  const u16* pbh = VCTh + ((size_t)b * 384 + col0 + rr) * 512 + kg * 8;
  const u16* pbl = VCTl + ((size_t)b * 384 + col0 + rr) * 512 + kg * 8;
  f32x4 acc[3] = {};
  float rs = 0.f;
  for (int k0 = w * 32; k0 < NN; k0 += 256) {
    bf16x8 a_h, a_l, b_h[3], b_l[3];
    {
      float v[8];
      *(float4*)&v[0] = *(const float4*)(pa + k0);
      *(float4*)&v[4] = *(const float4*)(pa + k0 + 4);
#pragma unroll
      for (int j = 0; j < 8; ++j) { float e = __expf(v[j] * SCALEF); rs += e; v[j] = e; }
      pack8(v, a_h, a_l);
    }
#pragma unroll
    for (int f = 0; f < 3; ++f) {
      b_h[f] = *(const bf16x8*)(pbh + (size_t)f * 16 * 512 + k0);
      b_l[f] = *(const bf16x8*)(pbl + (size_t)f * 16 * 512 + k0);
    }
#pragma unroll
    for (int f = 0; f < 3; ++f) { MFMA3(acc[f], a_h, a_l, b_h[f], b_l[f]) }
  }
  if (w) {
#pragma unroll
    for (int f = 0; f < 3; ++f) CB[w - 1][f][lane] = acc[f];
    RS[w - 1][lane] = rs;
  }
  __syncthreads();
  if (w) return;
#pragma unroll
  for (int wv = 0; wv < 7; ++wv) {
#pragma unroll
    for (int f = 0; f < 3; ++f) acc[f] += CB[wv][f][lane];
    rs += RS[wv][lane];
  }
  rs += __shfl_xor(rs, 16);
  rs += __shfl_xor(rs, 32);
  const int rb = (lane >> 4) << 2, cc = lane & 15;
  float inv[4];
#pragma unroll
  for (int r = 0; r < 4; ++r) inv[r] = 1.0f / __shfl(rs, rb + r);
#pragma unroll
  for (int f = 0; f < 3; ++f) {
    int n = col0 + f * 16 + cc;
    float bcv = bc[n];
#pragma unroll
    for (int r = 0; r < 4; ++r)
      out_res[((size_t)b * NN + row0 + rb + r) * 384 + n] = acc[f][r] * inv[r] + bcv;
  }
}

extern "C" void kernel_launch(void* const* d_in, const int* in_sizes, int n_in,
                              void* d_out, int out_size, void* d_ws, size_t ws_size,
                              hipStream_t stream) {
  const float* hidden = (const float*)d_in[0];
  const float* xyz   = (const float*)d_in[1];
  const float* W_qk  = (const float*)d_in[2];
  const float* b_qk  = (const float*)d_in[3];
  const float* W_vs  = (const float*)d_in[4];
  const float* b_vs  = (const float*)d_in[5];
  const float* W_so  = (const float*)d_in[6];
  const float* b_so  = (const float*)d_in[7];
  const float* W_pqk = (const float*)d_in[8];
  const float* b_pqk = (const float*)d_in[9];
  const float* W_pv  = (const float*)d_in[10];
  const float* b_pv  = (const float*)d_in[11];
  const float* W_po  = (const float*)d_in[12];
  const float* b_po  = (const float*)d_in[13];
  const float* W_fp  = (const float*)d_in[14];
  const float* b_fp  = (const float*)d_in[15];

  float* out_res = (float*)d_out;                  // [B,N,384]
  float* out_xyz = out_res + (size_t)BB * NN * 384;

  u16* p   = (u16*)d_ws;
  u16* QKh  = p;           p += 393216;   // 1024*384
  u16* QKl  = p;           p += 393216;
  u16* VRh  = p;           p += 491520;   // 1024*480
  u16* VRl  = p;           p += 491520;
  u16* VCTh = p;           p += 393216;   // 2*384*512
  u16* VCTl = p;           p += 393216;
  u16* WCTh = p;           p += 184320;   // 384*480
  u16* WCTl = p;           p += 184320;
  float* QPf  = (float*)p; p += 2 * 147456;  // 1024*144 f32
  float* ATTf = (float*)p; p += 2 * 524288;  // 2*512*512 f32
  float* VCdT = (float*)p; p += 2 * 3072;    // 2*3*512 f32
  float* bcf  = (float*)p; p += 2 * 384;
  float* Wdf  = (float*)p;                   // 867 f32

  k_input<<<dim3(29, 32), 512, 0, stream>>>(hidden,
                                            W_qk, b_qk, W_vs, b_vs, W_pv, b_pv, W_pqk, b_pqk,
                                            W_so, b_so, W_po, b_po, W_fp, b_fp,
                                            QKh, QKl, VRh, VRl, QPf, WCTh, WCTl, bcf, Wdf);
  k_attn<<<dim3(203, 1, 2), 512, 0, stream>>>(QKh, QKl, QPf, VRh, VRl,
                                              WCTh, WCTl, Wdf,
                                              ATTf, VCTh, VCTl, VCdT);
  k_pv_out<<<dim3(9, 32, 2), 512, 0, stream>>>(ATTf, VCTh, VCTl, VCdT, bcf, Wdf, xyz,
                                               out_res, out_xyz);
}

// Round 20
// 59.529 us; speedup vs baseline: 1.2603x; 1.2603x over previous
//
#include <hip/hip_runtime.h>
#include <math.h>

typedef unsigned short u16;
typedef __attribute__((ext_vector_type(8))) short bf16x8;
typedef __attribute__((ext_vector_type(4))) float f32x4;

#define BB 2
#define NN 512
#define SCALEF 0.17677669529663687f  // 1/sqrt(16 + 4*4)

__device__ __forceinline__ u16 f2bf(float x) {
  union { float f; unsigned u; } c; c.f = x;
  unsigned r = (c.u + 0x7FFFu + ((c.u >> 16) & 1u)) >> 16;
  return (u16)r;
}
__device__ __forceinline__ float bf2f(u16 h) {
  union { unsigned u; float f; } c; c.u = ((unsigned)h) << 16;
  return c.f;
}
__device__ __forceinline__ void pack8(const float* v, bf16x8& h, bf16x8& l) {
#pragma unroll
  for (int j = 0; j < 8; ++j) {
    u16 hi = f2bf(v[j]);
    h[j] = (short)hi;
    l[j] = (short)f2bf(v[j] - bf2f(hi));
  }
}
#define MFMA3(ACC, AH, AL, BH, BL)                                              \
  ACC = __builtin_amdgcn_mfma_f32_16x16x32_bf16(AH, BH, ACC, 0, 0, 0);          \
  ACC = __builtin_amdgcn_mfma_f32_16x16x32_bf16(AH, BL, ACC, 0, 0, 0);          \
  ACC = __builtin_amdgcn_mfma_f32_16x16x32_bf16(AL, BH, ACC, 0, 0, 0);

// ====== bf16 direct-global MFMA tile (used by k_attn QK) ======
template<int MR, int NF>
__device__ __forceinline__ void mfma_tile(
    const u16* __restrict__ Ah, const u16* __restrict__ Al, int lda,
    const u16* __restrict__ Bh, const u16* __restrict__ Bl, int ldb,
    int kBeg, int kEnd, int arow, int bcol, f32x4 (&acc)[MR][NF]) {
  const int lane = threadIdx.x & 63;
  const int rr = lane & 15, kg = lane >> 4;
  const u16* pah = Ah + (size_t)(arow + rr) * lda + kg * 8;
  const u16* pal = Al + (size_t)(arow + rr) * lda + kg * 8;
  const u16* pbh = Bh + (size_t)(bcol + rr) * ldb + kg * 8;
  const u16* pbl = Bl + (size_t)(bcol + rr) * ldb + kg * 8;
#pragma unroll 2
  for (int k0 = kBeg; k0 < kEnd; k0 += 32) {
    bf16x8 a_h[MR], a_l[MR], b_h[NF], b_l[NF];
#pragma unroll
    for (int m = 0; m < MR; ++m) {
      a_h[m] = *(const bf16x8*)(pah + (size_t)m * 16 * lda + k0);
      a_l[m] = *(const bf16x8*)(pal + (size_t)m * 16 * lda + k0);
    }
#pragma unroll
    for (int f = 0; f < NF; ++f) {
      b_h[f] = *(const bf16x8*)(pbh + (size_t)f * 16 * ldb + k0);
      b_l[f] = *(const bf16x8*)(pbl + (size_t)f * 16 * ldb + k0);
    }
#pragma unroll
    for (int m = 0; m < MR; ++m)
#pragma unroll
      for (int f = 0; f < NF; ++f) { MFMA3(acc[m][f], a_h[m], a_l[m], b_h[f], b_l[f]) }
  }
}

// ---------------- k_input: pure projection GEMMs (8-wave K-split) ----------------
__global__ __launch_bounds__(512) void k_input(
    const float* __restrict__ hidden,
    const float* __restrict__ W_qk, const float* __restrict__ b_qk,
    const float* __restrict__ W_vs, const float* __restrict__ b_vs,
    const float* __restrict__ W_pv, const float* __restrict__ b_pv,
    const float* __restrict__ W_pqk, const float* __restrict__ b_pqk,
    u16* __restrict__ QKh, u16* __restrict__ QKl,
    u16* __restrict__ VTh, u16* __restrict__ VTl,
    float* __restrict__ QPf) {
  const int tid = threadIdx.x;
  __shared__ f32x4 CB[7][2][3][64];
  __shared__ u16 Dh[48][32], Dl[48][32];
  const int w = tid >> 6, lane = tid & 63;
  const int rr = lane & 15, kg = lane >> 4;
  const int row0 = blockIdx.y * 32, col0 = blockIdx.x * 48;

  const float* W; const float* bias; int Ns, region;
  if (col0 < 384)      { W = W_qk;  Ns = 384; bias = b_qk + col0;          W += col0;       region = 0; }
  else if (col0 < 576) { W = W_vs;  Ns = 192; bias = b_vs + (col0 - 384);  W += col0 - 384; region = 1; }
  else if (col0 < 864) { W = W_pv;  Ns = 288; bias = b_pv + (col0 - 576);  W += col0 - 576; region = 1; }
  else                 { W = W_pqk; Ns = 144; bias = b_pqk + (col0 - 864); W += col0 - 864; region = 2; }

  f32x4 acc[2][3] = {};
  const float* pa = hidden + (size_t)(row0 + rr) * 384 + kg * 8;
  const float* pw = W + rr;
  for (int k0 = w * 32; k0 < 384; k0 += 256) {
    bf16x8 a_h[2], a_l[2], b_h[3], b_l[3];
#pragma unroll
    for (int m = 0; m < 2; ++m) {
      float v[8];
      *(float4*)&v[0] = *(const float4*)(pa + (size_t)m * 16 * 384 + k0);
      *(float4*)&v[4] = *(const float4*)(pa + (size_t)m * 16 * 384 + k0 + 4);
      pack8(v, a_h[m], a_l[m]);
    }
    const float* bp0 = pw + (size_t)(k0 + kg * 8) * Ns;
#pragma unroll
    for (int f = 0; f < 3; ++f) {
      float v[8];
#pragma unroll
      for (int j = 0; j < 8; ++j) v[j] = bp0[(size_t)j * Ns + f * 16];
      pack8(v, b_h[f], b_l[f]);
    }
#pragma unroll
    for (int m = 0; m < 2; ++m)
#pragma unroll
      for (int f = 0; f < 3; ++f) { MFMA3(acc[m][f], a_h[m], a_l[m], b_h[f], b_l[f]) }
  }
  if (w) {
#pragma unroll
    for (int m = 0; m < 2; ++m)
#pragma unroll
      for (int f = 0; f < 3; ++f) CB[w - 1][m][f][lane] = acc[m][f];
  }
  __syncthreads();
  if (w) return;
#pragma unroll
  for (int wv = 0; wv < 7; ++wv)
#pragma unroll
    for (int m = 0; m < 2; ++m)
#pragma unroll
      for (int f = 0; f < 3; ++f) acc[m][f] += CB[wv][m][f][lane];

  const int rb = (lane >> 4) << 2, cc = lane & 15;
  if (region == 0) {
#pragma unroll
    for (int f = 0; f < 3; ++f) {
      int n = col0 + f * 16 + cc;
      float bv = bias[f * 16 + cc];
#pragma unroll
      for (int m = 0; m < 2; ++m)
#pragma unroll
        for (int r = 0; r < 4; ++r) {
          float v = acc[m][f][r] + bv;
          int row = row0 + m * 16 + rb + r;
          u16 hi = f2bf(v);
          QKh[(size_t)row * 384 + n] = hi;
          QKl[(size_t)row * 384 + n] = f2bf(v - bf2f(hi));
        }
    }
  } else if (region == 2) {
#pragma unroll
    for (int f = 0; f < 3; ++f) {
      int c = (col0 - 864) + f * 16 + cc;
      float bv = bias[f * 16 + cc];
#pragma unroll
      for (int m = 0; m < 2; ++m)
#pragma unroll
        for (int r = 0; r < 4; ++r)
          QPf[(size_t)(row0 + m * 16 + rb + r) * 144 + c] = acc[m][f][r] + bv;
    }
  } else {
    // V region: transpose via LDS (single wave)
#pragma unroll
    for (int f = 0; f < 3; ++f) {
      float bv = bias[f * 16 + cc];
#pragma unroll
      for (int m = 0; m < 2; ++m)
#pragma unroll
        for (int r = 0; r < 4; ++r) {
          float v = acc[m][f][r] + bv;
          u16 hi = f2bf(v);
          Dh[f * 16 + cc][m * 16 + rb + r] = hi;
          Dl[f * 16 + cc][m * 16 + rb + r] = f2bf(v - bf2f(hi));
        }
    }
    const int b = row0 >> 9, rl = row0 & 511;
    const int cbase = col0 - 384;
    u16* dsth = VTh + (size_t)b * 480 * 512;
    u16* dstl = VTl + (size_t)b * 480 * 512;
    for (int u = lane; u < 192; u += 64) {
      int c = u >> 2, seg = u & 3;
      *(uint4*)(dsth + (size_t)(cbase + c) * 512 + rl + seg * 8) = *(const uint4*)&Dh[c][seg * 8];
      *(uint4*)(dstl + (size_t)(cbase + c) * 512 + rl + seg * 8) = *(const uint4*)&Dl[c][seg * 8];
    }
  }
}

// ---- k_attn: attn logits (136 tiles) + weight-composition blocks (96, z==0 only) ----
#define PROW 244
__global__ __launch_bounds__(512) void k_attn(
    const u16* __restrict__ QKh, const u16* __restrict__ QKl,
    const float* __restrict__ QPf,
    const float* __restrict__ W_so, const float* __restrict__ b_so,
    const float* __restrict__ W_po, const float* __restrict__ b_po,
    const float* __restrict__ W_fp, const float* __restrict__ b_fp,
    float* __restrict__ ATTf,
    u16* __restrict__ WCTh, u16* __restrict__ WCTl,
    float* __restrict__ bc, float* __restrict__ Wdf) {
  const int tid = threadIdx.x;
  const int b = blockIdx.z;
  if (blockIdx.x >= 136) {
    if (b) return;                        // compose once
    const int cx = blockIdx.x - 136;      // 0..95
    if (cx < 80) {
      // WCT tile: c in [(cx&7)*48,+48), k in [(cx>>3)*48,+48); contraction m=384
      const int w = tid >> 6, lane = tid & 63;
      if (w >= 3) return;
      const int rr = lane & 15, kg = lane >> 4;
      const int c0 = (cx & 7) * 48;
      const int kbase = (cx >> 3) * 48 + w * 16;
      const float* Wop; int moff;
      if (kbase < 192) { Wop = W_so + (size_t)kbase * 384; moff = 0; }
      else             { Wop = W_po + (size_t)(kbase - 192) * 384; moff = 384; }
      f32x4 acc[3] = {};
      const float* pa = Wop + (size_t)rr * 384 + kg * 8;
      const float* pw = W_fp + (size_t)moff * 384 + c0 + rr;
      for (int m0 = 0; m0 < 384; m0 += 32) {
        bf16x8 a_h, a_l, b_h[3], b_l[3];
        float v[8];
        *(float4*)&v[0] = *(const float4*)(pa + m0);
        *(float4*)&v[4] = *(const float4*)(pa + m0 + 4);
        pack8(v, a_h, a_l);
        const float* bp0 = pw + (size_t)(m0 + kg * 8) * 384;
#pragma unroll
        for (int f = 0; f < 3; ++f) {
          float u[8];
#pragma unroll
          for (int j = 0; j < 8; ++j) u[j] = bp0[(size_t)j * 384 + f * 16];
          pack8(u, b_h[f], b_l[f]);
        }
#pragma unroll
        for (int f = 0; f < 3; ++f) { MFMA3(acc[f], a_h, a_l, b_h[f], b_l[f]) }
      }
      const int rb = (lane >> 4) << 2, cc = lane & 15;
#pragma unroll
      for (int f = 0; f < 3; ++f) {
        int c = c0 + f * 16 + cc;
#pragma unroll
        for (int r = 0; r < 4; ++r) {
          int k = kbase + rb + r;
          float vv = acc[f][r];
          u16 hi = f2bf(vv);
          WCTh[(size_t)c * 480 + k] = hi;
          WCTl[(size_t)c * 480 + k] = f2bf(vv - bf2f(hi));
        }
      }
      return;
    }
    if (cx < 88) {
      // bc: 8 blocks x 48 cols; 8-way K-split
      const int colL = tid >> 3, part = tid & 7;
      if (colL >= 48) return;
      const int col = (cx - 80) * 48 + colL;
      const float* bv = (part < 4) ? b_so : b_po;
      const int m0 = (part & 3) * 96;
      const float* wrow = W_fp + (size_t)part * 96 * 384 + col;
      float s0 = 0.f, s1 = 0.f, s2 = 0.f, s3 = 0.f;
#pragma unroll
      for (int i = 0; i < 96; i += 4) {
        s0 += bv[m0 + i]     * wrow[(size_t)(i)     * 384];
        s1 += bv[m0 + i + 1] * wrow[(size_t)(i + 1) * 384];
        s2 += bv[m0 + i + 2] * wrow[(size_t)(i + 2) * 384];
        s3 += bv[m0 + i + 3] * wrow[(size_t)(i + 3) * 384];
      }
      float s = (s0 + s1) + (s2 + s3);
      s += __shfl_down(s, 4, 8);
      s += __shfl_down(s, 2, 8);
      s += __shfl_down(s, 1, 8);
      if (part == 0) bc[col] = s + b_fp[col];
      return;
    }
    {
      // Wd: 8 blocks x 36 j-rows x 3 comps; 4-way K-split (+bd on first block)
      const int bx = cx - 88;
      const int out = tid >> 2, part = tid & 3;
      if (out < 108) {
        const int j = bx * 36 + out / 3, c = out - (out / 3) * 3;
        const float* src = W_po + (size_t)j * 384 + c + (size_t)part * 96;
        float s0 = 0.f, s1 = 0.f;
#pragma unroll
        for (int kk = 0; kk < 32; kk += 2) {
          s0 += src[3 * kk];
          s1 += src[3 * kk + 3];
        }
        float s = s0 + s1;
        s += __shfl_down(s, 2, 4);
        s += __shfl_down(s, 1, 4);
        if (part == 0) Wdf[j * 3 + c] = s * (1.0f / 128.f);
      } else if (bx == 0 && tid >= 432 && tid < 480) {
        int g = tid - 432, c = g >> 4, k0 = g & 15;
        float s = 0.f;
#pragma unroll
        for (int kk = 0; kk < 8; ++kk) s += b_po[3 * (k0 * 8 + kk) + c];
        for (int d = 8; d; d >>= 1) s += __shfl_down(s, d, 16);
        if (k0 == 0) Wdf[864 + c] = s * (1.0f / 128.f);
      }
      return;
    }
  }
  // ---- attention logits path ----
  __shared__ float Pi[32][PROW];
  __shared__ float Pj[32][PROW];
  __shared__ float Sf[2][32 * 33];
  int t = blockIdx.x, ti_ = 0;
  while (t >= 16 - ti_) { t -= 16 - ti_; ++ti_; }
  const int tj_ = ti_ + t;
  const int i0 = ti_ * 32, j0 = tj_ * 32;
  const bool offdiag = (tj_ != ti_);
  for (int u = tid; u < 3072; u += 512) {
    int side = (u >= 1536) ? 1 : 0;
    int rem = u - side * 1536;
    int row = rem / 48, hp = rem - row * 48;
    int grow = b * NN + (side ? j0 : i0) + row;
    const float* p = QPf + (size_t)grow * 144 + hp * 3;
    float x = p[0], y = p[1], z = p[2];
    float n2 = x * x + y * y + z * z;
    float inv = __frsqrt_rn(n2 + 1e-12f);
    float* dst = side ? &Pj[row][0] : &Pi[row][0];
    ((float4*)dst)[hp] = make_float4(x, y, z, n2);
    dst[192 + hp] = inv;
  }
  __syncthreads();
  const int h = tid >> 8;
  const int t8 = tid & 255;
  const int tj = t8 & 15, ti = t8 >> 4;
  {
    float a00 = 0.f, a01 = 0.f, a10 = 0.f, a11 = 0.f;
    const float4* A0 = (const float4*)&Pi[ti][0];
    const float4* A1 = (const float4*)&Pi[ti + 16][0];
    const float4* B0 = (const float4*)&Pj[tj][0];
    const float4* B1 = (const float4*)&Pj[tj + 16][0];
    const float* iA0 = &Pi[ti][192];
    const float* iA1 = &Pi[ti + 16][192];
    const float* iB0 = &Pj[tj][192];
    const float* iB1 = &Pj[tj + 16][192];
    const int hpB = h * 24, hpE = hpB + 24;
#pragma unroll 4
    for (int hp = hpB; hp < hpE; ++hp) {
      float4 p0 = A0[hp], p1 = A1[hp], q0 = B0[hp], q1 = B1[hp];
      float va0 = iA0[hp], va1 = iA1[hp], vb0 = iB0[hp], vb1 = iB1[hp];
      {
        float dot = p0.x * q0.x + p0.y * q0.y + p0.z * q0.z;
        float d2 = fmaxf(fmaf(-2.f, dot, p0.w + q0.w), 0.f) + 1e-12f;
        a00 += d2 * __frsqrt_rn(d2) + dot * (va0 * vb0);
      }
      {
        float dot = p0.x * q1.x + p0.y * q1.y + p0.z * q1.z;
        float d2 = fmaxf(fmaf(-2.f, dot, p0.w + q1.w), 0.f) + 1e-12f;
        a01 += d2 * __frsqrt_rn(d2) + dot * (va0 * vb1);
      }
      {
        float dot = p1.x * q0.x + p1.y * q0.y + p1.z * q0.z;
        float d2 = fmaxf(fmaf(-2.f, dot, p1.w + q0.w), 0.f) + 1e-12f;
        a10 += d2 * __frsqrt_rn(d2) + dot * (va1 * vb0);
      }
      {
        float dot = p1.x * q1.x + p1.y * q1.y + p1.z * q1.z;
        float d2 = fmaxf(fmaf(-2.f, dot, p1.w + q1.w), 0.f) + 1e-12f;
        a11 += d2 * __frsqrt_rn(d2) + dot * (va1 * vb1);
      }
    }
    Sf[h][ti * 33 + tj] = a00;
    Sf[h][ti * 33 + tj + 16] = a01;
    Sf[h][(ti + 16) * 33 + tj] = a10;
    Sf[h][(ti + 16) * 33 + tj + 16] = a11;
  }
  const int w = tid >> 6, lane = tid & 63;
  const int dir = w >> 2, sub = w & 3;
  f32x4 q[1][1] = {};
  if (dir == 0) {
    int arow = b * NN + i0 + (sub >> 1) * 16;
    int brow = b * NN + j0 + (sub & 1) * 16;
    mfma_tile<1, 1>(QKh, QKl, 384, QKh + 192, QKl + 192, 384, 0, 192, arow, brow, q);
  } else if (offdiag) {
    int arow = b * NN + j0 + (sub >> 1) * 16;
    int brow = b * NN + i0 + (sub & 1) * 16;
    mfma_tile<1, 1>(QKh, QKl, 384, QKh + 192, QKl + 192, 384, 0, 192, arow, brow, q);
  }
  __syncthreads();
  const int rl = (sub >> 1) * 16 + ((lane >> 4) << 2);
  const int cl = (sub & 1) * 16 + (lane & 15);
  float* Cb = ATTf + (size_t)b * NN * NN;
  if (dir == 0) {
#pragma unroll
    for (int r = 0; r < 4; ++r)
      Cb[(size_t)(i0 + rl + r) * NN + j0 + cl] =
          q[0][0][r] + Sf[0][(rl + r) * 33 + cl] + Sf[1][(rl + r) * 33 + cl];
  } else if (offdiag) {
#pragma unroll
    for (int r = 0; r < 4; ++r)
      Cb[(size_t)(j0 + rl + r) * NN + i0 + cl] =
          q[0][0][r] + Sf[0][cl * 33 + rl + r] + Sf[1][cl * 33 + rl + r];
  }
}

// ---------------- k_pv: 8-wave K-split; exp-in-register, deferred normalization ----------------
__global__ __launch_bounds__(512) void k_pv(
    const float* __restrict__ ATTf,
    const u16* __restrict__ VTh, const u16* __restrict__ VTl,
    u16* __restrict__ SRh, u16* __restrict__ SRl) {
  __shared__ f32x4 CB[7][3][64];
  __shared__ float RS[7][64];
  const int tid = threadIdx.x;
  const int w = tid >> 6, lane = tid & 63;
  const int rr = lane & 15, kg = lane >> 4;
  const int b = blockIdx.z;
  const int row0 = blockIdx.y * 16, col0 = blockIdx.x * 48;
  const float* pa = ATTf + (size_t)(b * NN + row0 + rr) * NN + kg * 8;
  const u16* pbh = VTh + (size_t)b * 480 * 512 + (size_t)(col0 + rr) * 512 + kg * 8;
  const u16* pbl = VTl + (size_t)b * 480 * 512 + (size_t)(col0 + rr) * 512 + kg * 8;
  f32x4 acc[3] = {};
  float rs = 0.f;
  for (int k0 = w * 32; k0 < NN; k0 += 256) {
    bf16x8 a_h, a_l, b_h[3], b_l[3];
    {
      float v[8];
      *(float4*)&v[0] = *(const float4*)(pa + k0);
      *(float4*)&v[4] = *(const float4*)(pa + k0 + 4);
#pragma unroll
      for (int j = 0; j < 8; ++j) { float e = __expf(v[j] * SCALEF); rs += e; v[j] = e; }
      pack8(v, a_h, a_l);
    }
#pragma unroll
    for (int f = 0; f < 3; ++f) {
      b_h[f] = *(const bf16x8*)(pbh + (size_t)f * 16 * 512 + k0);
      b_l[f] = *(const bf16x8*)(pbl + (size_t)f * 16 * 512 + k0);
    }
#pragma unroll
    for (int f = 0; f < 3; ++f) { MFMA3(acc[f], a_h, a_l, b_h[f], b_l[f]) }
  }
  if (w) {
#pragma unroll
    for (int f = 0; f < 3; ++f) CB[w - 1][f][lane] = acc[f];
    RS[w - 1][lane] = rs;
  }
  __syncthreads();
  if (w) return;
#pragma unroll
  for (int wv = 0; wv < 7; ++wv) {
#pragma unroll
    for (int f = 0; f < 3; ++f) acc[f] += CB[wv][f][lane];
    rs += RS[wv][lane];
  }
  rs += __shfl_xor(rs, 16);
  rs += __shfl_xor(rs, 32);
  const int rb = (lane >> 4) << 2, cc = lane & 15;
  float inv[4];
#pragma unroll
  for (int r = 0; r < 4; ++r) inv[r] = 1.0f / __shfl(rs, rb + r);
  u16* oh = SRh + (size_t)b * NN * 480;
  u16* ol = SRl + (size_t)b * NN * 480;
#pragma unroll
  for (int f = 0; f < 3; ++f) {
    int n = col0 + f * 16 + cc;
#pragma unroll
    for (int r = 0; r < 4; ++r) {
      float v = acc[f][r] * inv[r];
      u16 hi = f2bf(v);
      oh[(size_t)(row0 + rb + r) * 480 + n] = hi;
      ol[(size_t)(row0 + rb + r) * 480 + n] = f2bf(v - bf2f(hi));
    }
  }
}

// ---------------- k_tail: out_res = SR @ WCT^T + bc ; out_xyz = xyz + SR_p @ Wd + bd ----------------
__global__ __launch_bounds__(512) void k_tail(
    const u16* __restrict__ SRh, const u16* __restrict__ SRl,
    const u16* __restrict__ WCTh, const u16* __restrict__ WCTl,
    const float* __restrict__ bc, const float* __restrict__ Wdf,
    const float* __restrict__ xyz,
    float* __restrict__ out_res, float* __restrict__ out_xyz) {
  const int tid = threadIdx.x;
  const int row0 = blockIdx.y * 16;
  if (blockIdx.x == 8) {
    if (tid < 384) {
      int out = tid >> 3, part = tid & 7;
      int lt = out / 3, c = out - lt * 3;
      int token = row0 + lt;
      const u16* sh = SRh + (size_t)token * 480 + 192 + part * 36;
      const u16* sl = SRl + (size_t)token * 480 + 192 + part * 36;
      float s = 0.f;
#pragma unroll 4
      for (int kk = 0; kk < 36; ++kk) {
        float v = bf2f(sh[kk]) + bf2f(sl[kk]);
        s += v * Wdf[(part * 36 + kk) * 3 + c];
      }
#pragma unroll
      for (int d = 4; d; d >>= 1) s += __shfl_down(s, d, 8);
      if (part == 0)
        out_xyz[(size_t)token * 3 + c] = xyz[(size_t)token * 3 + c] + s + Wdf[864 + c];
    }
    return;
  }
  __shared__ f32x4 CB[7][3][64];
  const int w = tid >> 6, lane = tid & 63;
  const int rr = lane & 15, kg = lane >> 4;
  const int col0 = blockIdx.x * 48;
  const u16* pah = SRh + (size_t)(row0 + rr) * 480 + kg * 8;
  const u16* pal = SRl + (size_t)(row0 + rr) * 480 + kg * 8;
  const u16* pbh = WCTh + (size_t)(col0 + rr) * 480 + kg * 8;
  const u16* pbl = WCTl + (size_t)(col0 + rr) * 480 + kg * 8;
  f32x4 acc[3] = {};
  for (int k0 = w * 32; k0 < 480; k0 += 256) {
    bf16x8 a_h, a_l, b_h[3], b_l[3];
    a_h = *(const bf16x8*)(pah + k0);
    a_l = *(const bf16x8*)(pal + k0);
#pragma unroll
    for (int f = 0; f < 3; ++f) {
      b_h[f] = *(const bf16x8*)(pbh + (size_t)f * 16 * 480 + k0);
      b_l[f] = *(const bf16x8*)(pbl + (size_t)f * 16 * 480 + k0);
    }
#pragma unroll
    for (int f = 0; f < 3; ++f) { MFMA3(acc[f], a_h, a_l, b_h[f], b_l[f]) }
  }
  if (w) {
#pragma unroll
    for (int f = 0; f < 3; ++f) CB[w - 1][f][lane] = acc[f];
  }
  __syncthreads();
  if (w) return;
#pragma unroll
  for (int wv = 0; wv < 7; ++wv)
#pragma unroll
    for (int f = 0; f < 3; ++f) acc[f] += CB[wv][f][lane];
  const int rb = (lane >> 4) << 2, cc = lane & 15;
#pragma unroll
  for (int f = 0; f < 3; ++f) {
    int n = col0 + f * 16 + cc;
#pragma unroll
    for (int r = 0; r < 4; ++r)
      out_res[(size_t)(row0 + rb + r) * 384 + n] = acc[f][r] + bc[n];
  }
}

extern "C" void kernel_launch(void* const* d_in, const int* in_sizes, int n_in,
                              void* d_out, int out_size, void* d_ws, size_t ws_size,
                              hipStream_t stream) {
  const float* hidden = (const float*)d_in[0];
  const float* xyz   = (const float*)d_in[1];
  const float* W_qk  = (const float*)d_in[2];
  const float* b_qk  = (const float*)d_in[3];
  const float* W_vs  = (const float*)d_in[4];
  const float* b_vs  = (const float*)d_in[5];
  const float* W_so  = (const float*)d_in[6];
  const float* b_so  = (const float*)d_in[7];
  const float* W_pqk = (const float*)d_in[8];
  const float* b_pqk = (const float*)d_in[9];
  const float* W_pv  = (const float*)d_in[10];
  const float* b_pv  = (const float*)d_in[11];
  const float* W_po  = (const float*)d_in[12];
  const float* b_po  = (const float*)d_in[13];
  const float* W_fp  = (const float*)d_in[14];
  const float* b_fp  = (const float*)d_in[15];

  float* out_res = (float*)d_out;                  // [B,N,384]
  float* out_xyz = out_res + (size_t)BB * NN * 384;

  u16* p   = (u16*)d_ws;
  u16* QKh  = p;           p += 393216;   // 1024*384
  u16* QKl  = p;           p += 393216;
  u16* VTh  = p;           p += 491520;   // 2*480*512
  u16* VTl  = p;           p += 491520;
  u16* SRh  = p;           p += 491520;   // 1024*480
  u16* SRl  = p;           p += 491520;
  u16* WCTh = p;           p += 184320;   // 384*480
  u16* WCTl = p;           p += 184320;
  float* QPf  = (float*)p; p += 2 * 147456;  // 1024*144 f32
  float* ATTf = (float*)p; p += 2 * 524288;  // 2*512*512 f32
  float* bcf  = (float*)p; p += 2 * 384;
  float* Wdf  = (float*)p;                   // 867 f32

  k_input<<<dim3(21, 32), 512, 0, stream>>>(hidden,
                                            W_qk, b_qk, W_vs, b_vs, W_pv, b_pv, W_pqk, b_pqk,
                                            QKh, QKl, VTh, VTl, QPf);
  k_attn<<<dim3(232, 1, 2), 512, 0, stream>>>(QKh, QKl, QPf,
                                              W_so, b_so, W_po, b_po, W_fp, b_fp,
                                              ATTf, WCTh, WCTl, bcf, Wdf);
  k_pv<<<dim3(10, 32, 2), 512, 0, stream>>>(ATTf, VTh, VTl, SRh, SRl);
  k_tail<<<dim3(9, 64), 512, 0, stream>>>(SRh, SRl, WCTh, WCTl, bcf, Wdf, xyz,
                                          out_res, out_xyz);
}